// Round 1
// baseline (68.034 us; speedup 1.0000x reference)
//
#include <hip/hip_runtime.h>

// TtLlamaRotary: out_q[n,s,:] = xq[n,s,:] @ R[s,:,:]   (n = 0..7)
//                out_k[s,:]   = xk[s,:]   @ R[s,:,:]
// S = 128, H(head_dim) = 128, all fp32.
// Memory-bound: rot_mat (8 MiB) read exactly once; ~9.2 MiB total traffic.

#define SEQ 128
#define HD  128
#define NQ  8
#define NH  9                    // 8 q heads + 1 k head fused
#define QOUT (NQ * SEQ * HD)     // 131072 floats, then k output follows

__global__ __launch_bounds__(128) void rotary_kernel(
    const float* __restrict__ xq,   // [8,128,128]
    const float* __restrict__ xk,   // [128,128]
    const float* __restrict__ rot,  // [128,128,128]  R[s][h][d]
    float* __restrict__ out)        // [131072 + 16384]
{
    const int bid  = blockIdx.x;    // 256 blocks = (s, half)
    const int s    = bid >> 1;
    const int half = bid & 1;
    const int tid  = threadIdx.x;   // 128 threads = 2 waves
    const int d4   = tid & 15;      // float4 index within this 64-d half
    const int hg   = tid >> 4;      // 8 h-groups of 16 h each

    __shared__ float  xs[NH * HD];  // staged x vectors, 4.6 KiB
    __shared__ float4 red[16 * NH]; // cross-wave partials, 2.3 KiB

    // Stage xq/xk rows for this s into LDS (coalesced: consecutive tid -> consecutive h).
    for (int i = tid; i < NH * HD; i += 128) {
        const int head = i >> 7;       // i / HD
        const int h    = i & (HD - 1);
        xs[i] = (head < NQ) ? xq[((size_t)head * SEQ + s) * HD + h]
                            : xk[(size_t)s * HD + h];
    }
    __syncthreads();

    const float4* Rrow = (const float4*)(rot + (size_t)s * HD * HD); // 32 float4 per h-row
    const int doff = half * 16 + d4;  // float4 offset within a row

    float4 acc[NH];
#pragma unroll
    for (int n = 0; n < NH; ++n) acc[n] = make_float4(0.f, 0.f, 0.f, 0.f);

    // h = 8*i + hg : interleaved so the 4 distinct LDS broadcast addresses per
    // wave fall in consecutive banks (conflict-free), and R rows stay coalesced.
#pragma unroll
    for (int i = 0; i < 16; ++i) {
        const int h = i * 8 + hg;
        const float4 r = Rrow[h * 32 + doff];
#pragma unroll
        for (int n = 0; n < NH; ++n) {
            const float x = xs[n * HD + h];
            acc[n].x += x * r.x;
            acc[n].y += x * r.y;
            acc[n].z += x * r.z;
            acc[n].w += x * r.w;
        }
    }

    // Reduce over the 4 h-groups inside each wave: xor-16 then xor-32 butterfly.
#pragma unroll
    for (int mask = 16; mask <= 32; mask <<= 1) {
#pragma unroll
        for (int n = 0; n < NH; ++n) {
            acc[n].x += __shfl_xor(acc[n].x, mask, 64);
            acc[n].y += __shfl_xor(acc[n].y, mask, 64);
            acc[n].z += __shfl_xor(acc[n].z, mask, 64);
            acc[n].w += __shfl_xor(acc[n].w, mask, 64);
        }
    }

    // Cross-wave combine: wave 1's reduced lanes park in LDS, wave 0 finishes.
    if (tid >= 64 && tid < 80) {
#pragma unroll
        for (int n = 0; n < NH; ++n) red[d4 * NH + n] = acc[n];
    }
    __syncthreads();

    if (tid < 16) {
        const int dbase = half * 64 + d4 * 4;
#pragma unroll
        for (int n = 0; n < NH; ++n) {
            const float4 o = red[d4 * NH + n];
            float4 a = acc[n];
            a.x += o.x; a.y += o.y; a.z += o.z; a.w += o.w;
            float* dst = (n < NQ)
                ? (out + ((size_t)n * SEQ + s) * HD + dbase)
                : (out + QOUT + (size_t)s * HD + dbase);
            *(float4*)dst = a;
        }
    }
}

extern "C" void kernel_launch(void* const* d_in, const int* in_sizes, int n_in,
                              void* d_out, int out_size, void* d_ws, size_t ws_size,
                              hipStream_t stream) {
    const float* xq  = (const float*)d_in[0];  // [1,8,128,128]
    const float* xk  = (const float*)d_in[1];  // [1,1,128,128]
    const float* rot = (const float*)d_in[2];  // [1,128,128,128]
    float* out = (float*)d_out;                // q out (131072) ++ k out (16384)
    rotary_kernel<<<dim3(SEQ * 2), dim3(128), 0, stream>>>(xq, xk, rot, out);
}

// Round 4
// 67.877 us; speedup vs baseline: 1.0023x; 1.0023x over previous
//
#include <hip/hip_runtime.h>

// TtLlamaRotary: out_q[n,s,:] = xq[n,s,:] @ R[s,:,:]   (n = 0..7)
//                out_k[s,:]   = xk[s,:]   @ R[s,:,:]
// S = 128, HD = 128, fp32. Memory-bound: rot (8 MiB) read exactly once.
//
// R4: R2/R3 aborted on an HSA memory fault: grid was 512 but decode was
// s = bid>>1 -> s up to 255 (SEQ=128) -> OOB rot reads / out writes.
// Fixed decomposition: 512 blocks = (s, d-quarter), s = bid>>2.
// 256 threads/block -> 2 blocks/CU, 8 waves/CU; per-lane load chain of 4.

#define SEQ 128
#define HD  128
#define NQ  8
#define NH  9                    // 8 q heads + 1 k head fused
#define QOUT (NQ * SEQ * HD)

__global__ __launch_bounds__(256) void rotary_kernel(
    const float* __restrict__ xq,   // [8,128,128]
    const float* __restrict__ xk,   // [128,128]
    const float* __restrict__ rot,  // [128,128,128]  R[s][h][d]
    float* __restrict__ out)        // q (131072) ++ k (16384)
{
    const int bid  = blockIdx.x;    // 512 blocks = (s, quarter)
    const int s    = bid >> 2;      // 0..127  (grid/decode consistency audited!)
    const int qtr  = bid & 3;       // 0..3 -> 32 d columns each
    const int tid  = threadIdx.x;   // 256 threads = 4 waves
    const int d4   = tid & 7;       // float4 index within this 32-d quarter
    const int hg   = tid >> 3;      // 32 h-groups of 4 h each
    const int w    = tid >> 6;      // wave id 0..3
    const int lane = tid & 63;

    __shared__ float  xs[NH * HD];     // staged x vectors, 4.6 KiB
    __shared__ float4 red[4][8][NH];   // per-wave partials, 4.6 KiB

    // Stage xq/xk rows for this s (coalesced: consecutive tid -> consecutive h).
    for (int i = tid; i < NH * HD; i += 256) {
        const int head = i >> 7;
        const int h    = i & (HD - 1);
        xs[i] = (head < NQ) ? xq[((size_t)head * SEQ + s) * HD + h]
                            : xk[(size_t)s * HD + h];
    }
    __syncthreads();

    const float4* Rrow = (const float4*)(rot + (size_t)s * HD * HD); // 32 float4/h-row
    const int doff = qtr * 8 + d4;      // 0..31

    float4 acc[NH];
#pragma unroll
    for (int n = 0; n < NH; ++n) acc[n] = make_float4(0.f, 0.f, 0.f, 0.f);

    // h = i*32 + hg: per-lane chain of 4 independent loads; for fixed i a wave
    // reads 8 h-rows x 128 B contiguous segments (full cache lines).
#pragma unroll
    for (int i = 0; i < 4; ++i) {
        const int h = i * 32 + hg;                 // 0..127
        const float4 r = Rrow[h * 32 + doff];      // max 127*32+31 = 4095
#pragma unroll
        for (int n = 0; n < NH; ++n) {
            const float x = xs[n * HD + h];
            acc[n].x += x * r.x;
            acc[n].y += x * r.y;
            acc[n].z += x * r.z;
            acc[n].w += x * r.w;
        }
    }

    // In-wave reduce over the 8 resident hg groups (lane bits 3..5).
#pragma unroll
    for (int mask = 8; mask <= 32; mask <<= 1) {
#pragma unroll
        for (int n = 0; n < NH; ++n) {
            acc[n].x += __shfl_xor(acc[n].x, mask, 64);
            acc[n].y += __shfl_xor(acc[n].y, mask, 64);
            acc[n].z += __shfl_xor(acc[n].z, mask, 64);
            acc[n].w += __shfl_xor(acc[n].w, mask, 64);
        }
    }

    // Park each wave's reduced partial (lanes 0..7 hold full wave sums).
    if (lane < 8) {
#pragma unroll
        for (int n = 0; n < NH; ++n) red[w][lane][n] = acc[n];
    }
    __syncthreads();

    // 72 threads finish one (head, d4) each: sum 4 wave partials, store.
    if (tid < NH * 8) {
        const int n  = tid >> 3;   // 0..8
        const int dd = tid & 7;    // 0..7
        float4 a = red[0][dd][n];
#pragma unroll
        for (int ww = 1; ww < 4; ++ww) {
            const float4 o = red[ww][dd][n];
            a.x += o.x; a.y += o.y; a.z += o.z; a.w += o.w;
        }
        const int dbase = qtr * 32 + dd * 4;       // 0..124
        float* dst = (n < NQ)
            ? (out + ((size_t)n * SEQ + s) * HD + dbase)
            : (out + QOUT + (size_t)s * HD + dbase);
        *(float4*)dst = a;
    }
}

extern "C" void kernel_launch(void* const* d_in, const int* in_sizes, int n_in,
                              void* d_out, int out_size, void* d_ws, size_t ws_size,
                              hipStream_t stream) {
    const float* xq  = (const float*)d_in[0];  // [1,8,128,128]
    const float* xk  = (const float*)d_in[1];  // [1,1,128,128]
    const float* rot = (const float*)d_in[2];  // [1,128,128,128]
    float* out = (float*)d_out;
    rotary_kernel<<<dim3(SEQ * 4), dim3(256), 0, stream>>>(xq, xk, rot, out);
}